// Round 1
// baseline (16296.307 us; speedup 1.0000x reference)
//
#include <hip/hip_runtime.h>
#include <math.h>

#define B_  16
#define D_  2048
#define T_  100
#define N0_ 4096
#define N1_ 4096
#define N2_ 2048
#define NC_ 10

// ---------------- rates = sigmoid(x @ W_enc + b_enc) ----------------
__global__ __launch_bounds__(256) void rates_kernel(
    const float* __restrict__ x, const float* __restrict__ W_enc,
    const float* __restrict__ b_enc, float* __restrict__ rates)
{
    int tid = blockIdx.x * 256 + threadIdx.x;      // 65536 = B*N0
    int b = tid >> 12, i = tid & (N0_ - 1);
    const float* xr = x + b * D_;
    float acc = 0.f;
    for (int d = 0; d < D_; ++d)
        acc = fmaf(xr[d], W_enc[(size_t)d * N0_ + i], acc);
    float z = __fadd_rn(acc, b_enc[i]);
    rates[tid] = 1.0f / (1.0f + expf(-z));         // (B, N0)
}

// ---- layer-0 LIF over all T (independent of weights): s0, p0 in (T,N0,B) ----
__global__ __launch_bounds__(256) void layer0_kernel(
    const float* __restrict__ u, const float* __restrict__ rates,
    float* __restrict__ s0_all, float* __restrict__ p0_all)
{
    int tid = blockIdx.x * 256 + threadIdx.x;      // 65536
    int b = tid & (B_ - 1), i = tid >> 4;
    float rate = rates[b * N0_ + i];
    const float* ub = u + (size_t)b * T_ * N0_ + i;  // u is (B,T,N0)
    float V = 0.f, refr = 0.f, p0 = 0.f;
    for (int t = 0; t < T_; ++t) {
        float uv = ub[(size_t)t * N0_];
        float s_in = (uv < rate) ? 1.0f : 0.0f;
        V = __fadd_rn(__fmul_rn(0.9f, V), s_in);
        bool spk = (V > 1.0f) && (refr <= 0.0f);
        float s = spk ? 1.0f : 0.0f;
        V = spk ? 0.0f : V;
        refr = spk ? 2.0f : fmaxf(refr - 1.0f, 0.0f);
        p0 = __fadd_rn(__fmul_rn(0.95f, p0), s);   // trace after spike, per reference
        size_t idx = ((size_t)t * N0_ + i) * B_ + b;
        s0_all[idx] = s;
        p0_all[idx] = p0;
    }
}

// ---- fused: apply dWa(t-1)+clip, then partial y1(t) = s0(t) @ Wa ----
// grid 512: 16 j-tiles(256) x 32 i-chunks(128). Partials pa: (32,B,N1).
__global__ __launch_bounds__(256) void ka_kernel(
    float* __restrict__ Wa,            // (N0, N1) in-place
    const float* __restrict__ s0_all,  // (T, N0, B)
    const float* __restrict__ p0_all,  // (T, N0, B)
    const float* __restrict__ s1_bj,   // (2, B, N1)
    const float* __restrict__ q0_bj,   // (2, B, N1)
    float* __restrict__ pa, int t)
{
    const int jt = blockIdx.x & 15;
    const int chunk = blockIdx.x >> 4;
    const int j = jt * 256 + threadIdx.x;
    const int i0 = chunk * 128;
    const int prev = 1 - (t & 1);

    float acc[B_];
    #pragma unroll
    for (int b = 0; b < B_; ++b) acc[b] = 0.f;

    const float* s0t = s0_all + (size_t)t * N0_ * B_;

    if (t > 0) {
        float s1v[B_], q0v[B_];
        #pragma unroll
        for (int b = 0; b < B_; ++b) {
            s1v[b] = s1_bj[((size_t)prev * B_ + b) * N1_ + j];
            q0v[b] = q0_bj[((size_t)prev * B_ + b) * N1_ + j];
        }
        const float* s0p = s0_all + (size_t)(t - 1) * N0_ * B_;
        const float* p0p = p0_all + (size_t)(t - 1) * N0_ * B_;
        for (int ii = 0; ii < 128; ++ii) {
            const int i = i0 + ii;
            const float* p0r  = p0p + (size_t)i * B_;   // wave-uniform 64B rows
            const float* s0r  = s0p + (size_t)i * B_;
            const float* s0tr = s0t + (size_t)i * B_;
            float w = Wa[(size_t)i * N1_ + j];
            float t1 = 0.f, t2 = 0.f;
            #pragma unroll
            for (int b = 0; b < B_; ++b) {
                t1 = fmaf(p0r[b], s1v[b], t1);   // products exact (s1 binary)
                t2 = fmaf(s0r[b], q0v[b], t2);   // products exact (s0 binary)
            }
            float wn = __fadd_rn(w, __fmul_rn(0.01f, __fsub_rn(t1, t2)));
            wn = fminf(fmaxf(wn, -1.0f), 1.0f);
            Wa[(size_t)i * N1_ + j] = wn;
            #pragma unroll
            for (int b = 0; b < B_; ++b) acc[b] = fmaf(s0tr[b], wn, acc[b]);
        }
    } else {
        for (int ii = 0; ii < 128; ++ii) {
            const int i = i0 + ii;
            const float* s0tr = s0t + (size_t)i * B_;
            float w = Wa[(size_t)i * N1_ + j];
            #pragma unroll
            for (int b = 0; b < B_; ++b) acc[b] = fmaf(s0tr[b], w, acc[b]);
        }
    }
    #pragma unroll
    for (int b = 0; b < B_; ++b)
        pa[((size_t)chunk * B_ + b) * N1_ + j] = acc[b];
}

// ---- LIF layer 1: reduce pa (fixed order), V1/r1, s1, q0, p1 ----
__global__ __launch_bounds__(256) void lif1_kernel(
    const float* __restrict__ pa, float* __restrict__ V1, float* __restrict__ r1,
    float* __restrict__ s1_bj, float* __restrict__ s1_jb,
    float* __restrict__ q0_bj, float* __restrict__ p1_jb, int t)
{
    int tid = blockIdx.x * 256 + threadIdx.x;      // 65536 = B*N1
    int b = tid >> 12, j = tid & (N1_ - 1);
    float y = 0.f;
    for (int c = 0; c < 32; ++c) y += pa[((size_t)c * B_ + b) * N1_ + j];
    float V = __fadd_rn(__fmul_rn(0.9f, V1[tid]), y);
    float rr = r1[tid];
    bool spk = (V > 1.0f) && (rr <= 0.0f);
    float s = spk ? 1.0f : 0.0f;
    V1[tid] = spk ? 0.0f : V;
    r1[tid] = spk ? 2.0f : fmaxf(rr - 1.0f, 0.0f);
    int cur = t & 1, prev = 1 - cur;
    s1_bj[(size_t)cur * B_ * N1_ + tid] = s;
    s1_jb[(size_t)cur * B_ * N1_ + (size_t)j * B_ + b] = s;
    float q0 = __fadd_rn(__fmul_rn(0.95f, q0_bj[(size_t)prev * B_ * N1_ + tid]), s);
    q0_bj[(size_t)cur * B_ * N1_ + tid] = q0;
    float p1 = __fadd_rn(__fmul_rn(0.95f, p1_jb[(size_t)prev * B_ * N1_ + (size_t)j * B_ + b]), s);
    p1_jb[(size_t)cur * B_ * N1_ + (size_t)j * B_ + b] = p1;
}

// ---- fused: apply dWb(t-1)+clip, then partial y2(t) = s1(t) @ Wb ----
// grid 512: 8 k-tiles(256) x 64 j-chunks(64). Partials pb: (64,B,N2).
__global__ __launch_bounds__(256) void kb_kernel(
    float* __restrict__ Wb,            // (N1, N2) in-place
    const float* __restrict__ s1_jb,   // (2, N1, B)
    const float* __restrict__ p1_jb,   // (2, N1, B)
    const float* __restrict__ s2_bk,   // (2, B, N2)
    const float* __restrict__ q1_bk,   // (2, B, N2)
    float* __restrict__ pb, int t)
{
    const int kt = blockIdx.x & 7;
    const int chunk = blockIdx.x >> 3;
    const int k = kt * 256 + threadIdx.x;
    const int j0 = chunk * 64;
    const int cur = t & 1, prev = 1 - cur;

    float acc[B_];
    #pragma unroll
    for (int b = 0; b < B_; ++b) acc[b] = 0.f;

    const float* s1c = s1_jb + (size_t)cur * N1_ * B_;

    if (t > 0) {
        float s2v[B_], q1v[B_];
        #pragma unroll
        for (int b = 0; b < B_; ++b) {
            s2v[b] = s2_bk[((size_t)prev * B_ + b) * N2_ + k];
            q1v[b] = q1_bk[((size_t)prev * B_ + b) * N2_ + k];
        }
        const float* p1p = p1_jb + (size_t)prev * N1_ * B_;
        const float* s1p = s1_jb + (size_t)prev * N1_ * B_;
        for (int jj = j0; jj < j0 + 64; ++jj) {
            const float* p1r  = p1p + (size_t)jj * B_;
            const float* s1pr = s1p + (size_t)jj * B_;
            const float* s1cr = s1c + (size_t)jj * B_;
            float w = Wb[(size_t)jj * N2_ + k];
            float t1 = 0.f, t2 = 0.f;
            #pragma unroll
            for (int b = 0; b < B_; ++b) {
                t1 = fmaf(p1r[b], s2v[b], t1);
                t2 = fmaf(s1pr[b], q1v[b], t2);
            }
            float wn = __fadd_rn(w, __fmul_rn(0.01f, __fsub_rn(t1, t2)));
            wn = fminf(fmaxf(wn, -1.0f), 1.0f);
            Wb[(size_t)jj * N2_ + k] = wn;
            #pragma unroll
            for (int b = 0; b < B_; ++b) acc[b] = fmaf(s1cr[b], wn, acc[b]);
        }
    } else {
        for (int jj = j0; jj < j0 + 64; ++jj) {
            const float* s1cr = s1c + (size_t)jj * B_;
            float w = Wb[(size_t)jj * N2_ + k];
            #pragma unroll
            for (int b = 0; b < B_; ++b) acc[b] = fmaf(s1cr[b], w, acc[b]);
        }
    }
    #pragma unroll
    for (int b = 0; b < B_; ++b)
        pb[((size_t)chunk * B_ + b) * N2_ + k] = acc[b];
}

// ---- LIF layer 2: reduce pb, V2/r2, s2, q1, spike counts ----
__global__ __launch_bounds__(256) void lif2_kernel(
    const float* __restrict__ pb, float* __restrict__ V2, float* __restrict__ r2,
    float* __restrict__ s2_bk, float* __restrict__ q1_bk,
    float* __restrict__ counts, int t)
{
    int tid = blockIdx.x * 256 + threadIdx.x;      // 32768 = B*N2
    int b = tid >> 11, k = tid & (N2_ - 1);
    float y = 0.f;
    for (int c = 0; c < 64; ++c) y += pb[((size_t)c * B_ + b) * N2_ + k];
    float V = __fadd_rn(__fmul_rn(0.9f, V2[tid]), y);
    float rr = r2[tid];
    bool spk = (V > 1.0f) && (rr <= 0.0f);
    float s = spk ? 1.0f : 0.0f;
    V2[tid] = spk ? 0.0f : V;
    r2[tid] = spk ? 2.0f : fmaxf(rr - 1.0f, 0.0f);
    int cur = t & 1, prev = 1 - cur;
    s2_bk[(size_t)cur * B_ * N2_ + tid] = s;
    float q1 = __fadd_rn(__fmul_rn(0.95f, q1_bk[(size_t)prev * B_ * N2_ + tid]), s);
    q1_bk[(size_t)cur * B_ * N2_ + tid] = q1;
    counts[tid] = counts[tid] + s;
}

// ---- decode: out = counts @ W_dec + b_dec ----
__global__ __launch_bounds__(256) void decode_kernel(
    const float* __restrict__ counts, const float* __restrict__ W_dec,
    const float* __restrict__ b_dec, float* __restrict__ out)
{
    int tid = threadIdx.x;
    if (tid < B_ * NC_) {
        int b = tid / NC_, c = tid % NC_;
        float a = 0.f;
        for (int k = 0; k < N2_; ++k)
            a = fmaf(counts[(size_t)b * N2_ + k], W_dec[(size_t)k * NC_ + c], a);
        out[tid] = __fadd_rn(a, b_dec[c]);
    }
}

extern "C" void kernel_launch(void* const* d_in, const int* in_sizes, int n_in,
                              void* d_out, int out_size, void* d_ws, size_t ws_size,
                              hipStream_t stream) {
    const float* x     = (const float*)d_in[0];
    const float* u     = (const float*)d_in[1];
    const float* W_enc = (const float*)d_in[2];
    const float* b_enc = (const float*)d_in[3];
    float* Wa          = (float*)d_in[4];   // updated in place; harness restores before every timed launch
    float* Wb          = (float*)d_in[5];
    const float* W_dec = (const float*)d_in[6];
    const float* b_dec = (const float*)d_in[7];
    float* out         = (float*)d_out;

    float* ws = (float*)d_ws;
    size_t off = 0;
    float* rates  = ws + off; off += (size_t)B_ * N0_;
    float* s0_all = ws + off; off += (size_t)T_ * N0_ * B_;
    float* p0_all = ws + off; off += (size_t)T_ * N0_ * B_;
    float* s1_bj  = ws + off; off += 2 * (size_t)B_ * N1_;
    float* s1_jb  = ws + off; off += 2 * (size_t)B_ * N1_;
    float* pa     = ws + off; off += 32 * (size_t)B_ * N1_;
    float* pb     = ws + off; off += 64 * (size_t)B_ * N2_;
    float* zblock = ws + off;                       // everything below is zero-init state
    float* q0_bj  = ws + off; off += 2 * (size_t)B_ * N1_;
    float* p1_jb  = ws + off; off += 2 * (size_t)B_ * N1_;
    float* q1_bk  = ws + off; off += 2 * (size_t)B_ * N2_;
    float* s2_bk  = ws + off; off += 2 * (size_t)B_ * N2_;
    float* V1     = ws + off; off += (size_t)B_ * N1_;
    float* r1     = ws + off; off += (size_t)B_ * N1_;
    float* V2     = ws + off; off += (size_t)B_ * N2_;
    float* r2     = ws + off; off += (size_t)B_ * N2_;
    float* counts = ws + off; off += (size_t)B_ * N2_;
    size_t zbytes = (size_t)((ws + off) - zblock) * sizeof(float);

    hipMemsetAsync(zblock, 0, zbytes, stream);
    rates_kernel<<<256, 256, 0, stream>>>(x, W_enc, b_enc, rates);
    layer0_kernel<<<256, 256, 0, stream>>>(u, rates, s0_all, p0_all);
    for (int t = 0; t < T_; ++t) {
        ka_kernel<<<512, 256, 0, stream>>>(Wa, s0_all, p0_all, s1_bj, q0_bj, pa, t);
        lif1_kernel<<<256, 256, 0, stream>>>(pa, V1, r1, s1_bj, s1_jb, q0_bj, p1_jb, t);
        kb_kernel<<<512, 256, 0, stream>>>(Wb, s1_jb, p1_jb, s2_bk, q1_bk, pb, t);
        lif2_kernel<<<128, 256, 0, stream>>>(pb, V2, r2, s2_bk, q1_bk, counts, t);
    }
    decode_kernel<<<1, 256, 0, stream>>>(counts, W_dec, b_dec, out);
}

// Round 2
// 11896.626 us; speedup vs baseline: 1.3698x; 1.3698x over previous
//
#include <hip/hip_runtime.h>
#include <math.h>

#define B_  16
#define D_  2048
#define T_  100
#define N0_ 4096
#define N1_ 4096
#define N2_ 2048
#define NC_ 10

// ---------------- rates = sigmoid(x @ W_enc + b_enc) ----------------
__global__ __launch_bounds__(256) void rates_kernel(
    const float* __restrict__ x, const float* __restrict__ W_enc,
    const float* __restrict__ b_enc, float* __restrict__ rates)
{
    int tid = blockIdx.x * 256 + threadIdx.x;      // 65536 = B*N0
    int b = tid >> 12, i = tid & (N0_ - 1);
    const float* xr = x + b * D_;
    float acc = 0.f;
    for (int d = 0; d < D_; ++d)
        acc = fmaf(xr[d], W_enc[(size_t)d * N0_ + i], acc);
    float z = __fadd_rn(acc, b_enc[i]);
    rates[tid] = 1.0f / (1.0f + expf(-z));         // (B, N0)
}

// ---- layer-0 LIF over all T (independent of weights): s0, p0 in (T,N0,B) ----
__global__ __launch_bounds__(256) void layer0_kernel(
    const float* __restrict__ u, const float* __restrict__ rates,
    float* __restrict__ s0_all, float* __restrict__ p0_all)
{
    int tid = blockIdx.x * 256 + threadIdx.x;      // 65536
    int b = tid & (B_ - 1), i = tid >> 4;
    float rate = rates[b * N0_ + i];
    const float* ub = u + (size_t)b * T_ * N0_ + i;  // u is (B,T,N0)
    float V = 0.f, refr = 0.f, p0 = 0.f;
    for (int t = 0; t < T_; ++t) {
        float uv = ub[(size_t)t * N0_];
        float s_in = (uv < rate) ? 1.0f : 0.0f;
        V = __fadd_rn(__fmul_rn(0.9f, V), s_in);
        bool spk = (V > 1.0f) && (refr <= 0.0f);
        float s = spk ? 1.0f : 0.0f;
        V = spk ? 0.0f : V;
        refr = spk ? 2.0f : fmaxf(refr - 1.0f, 0.0f);
        p0 = __fadd_rn(__fmul_rn(0.95f, p0), s);   // trace after spike, per reference
        size_t idx = ((size_t)t * N0_ + i) * B_ + b;
        s0_all[idx] = s;
        p0_all[idx] = p0;
    }
}

// dot16 in fixed b-ascending order (bitwise == round-0 chain)
__device__ __forceinline__ float dot16(const float4 r[4], const float* v) {
    float t = 0.f;
    t = fmaf(r[0].x, v[0], t);  t = fmaf(r[0].y, v[1], t);
    t = fmaf(r[0].z, v[2], t);  t = fmaf(r[0].w, v[3], t);
    t = fmaf(r[1].x, v[4], t);  t = fmaf(r[1].y, v[5], t);
    t = fmaf(r[1].z, v[6], t);  t = fmaf(r[1].w, v[7], t);
    t = fmaf(r[2].x, v[8], t);  t = fmaf(r[2].y, v[9], t);
    t = fmaf(r[2].z, v[10], t); t = fmaf(r[2].w, v[11], t);
    t = fmaf(r[3].x, v[12], t); t = fmaf(r[3].y, v[13], t);
    t = fmaf(r[3].z, v[14], t); t = fmaf(r[3].w, v[15], t);
    return t;
}
__device__ __forceinline__ void acc16(float* acc, const float4 r[4], float w) {
    acc[0]  = fmaf(r[0].x, w, acc[0]);  acc[1]  = fmaf(r[0].y, w, acc[1]);
    acc[2]  = fmaf(r[0].z, w, acc[2]);  acc[3]  = fmaf(r[0].w, w, acc[3]);
    acc[4]  = fmaf(r[1].x, w, acc[4]);  acc[5]  = fmaf(r[1].y, w, acc[5]);
    acc[6]  = fmaf(r[1].z, w, acc[6]);  acc[7]  = fmaf(r[1].w, w, acc[7]);
    acc[8]  = fmaf(r[2].x, w, acc[8]);  acc[9]  = fmaf(r[2].y, w, acc[9]);
    acc[10] = fmaf(r[2].z, w, acc[10]); acc[11] = fmaf(r[2].w, w, acc[11]);
    acc[12] = fmaf(r[3].x, w, acc[12]); acc[13] = fmaf(r[3].y, w, acc[13]);
    acc[14] = fmaf(r[3].z, w, acc[14]); acc[15] = fmaf(r[3].w, w, acc[15]);
}
__device__ __forceinline__ void ld_row4(float4 r[4], const float* p) {
    const float4* p4 = (const float4*)p;   // 64B-aligned (i*B_*4)
    r[0] = p4[0]; r[1] = p4[1]; r[2] = p4[2]; r[3] = p4[3];
}

// ---- fused: apply dWa(t-1)+clip, then partial y1(t) = s0(t) @ Wa ----
// grid 256: 8 j-tiles(512, JT=2) x 32 i-chunks(128). Partials pa: (32,B,N1).
// Chunk boundaries + all FMA chain orders identical to round 0 (bitwise).
__global__ __launch_bounds__(256) void ka_kernel(
    float* __restrict__ Wa,            // (N0, N1) in-place
    const float* __restrict__ s0_all,  // (T, N0, B)
    const float* __restrict__ p0_all,  // (T, N0, B)
    const float* __restrict__ s1_bj,   // (2, B, N1)
    const float* __restrict__ q0_bj,   // (2, B, N1)
    float* __restrict__ pa, int t, int store_w)
{
    const int jt = blockIdx.x >> 5;         // 0..7
    const int chunk = blockIdx.x & 31;      // 0..31
    const int j0 = jt * 512 + threadIdx.x;
    const int j1 = j0 + 256;
    const int i0 = chunk * 128;
    const int prev = 1 - (t & 1);

    float acc0[B_], acc1[B_];
    #pragma unroll
    for (int b = 0; b < B_; ++b) { acc0[b] = 0.f; acc1[b] = 0.f; }

    const float* s0t = s0_all + (size_t)t * N0_ * B_;

    if (t > 0) {
        float s1v0[B_], q0v0[B_], s1v1[B_], q0v1[B_];
        #pragma unroll
        for (int b = 0; b < B_; ++b) {
            s1v0[b] = s1_bj[((size_t)prev * B_ + b) * N1_ + j0];
            q0v0[b] = q0_bj[((size_t)prev * B_ + b) * N1_ + j0];
            s1v1[b] = s1_bj[((size_t)prev * B_ + b) * N1_ + j1];
            q0v1[b] = q0_bj[((size_t)prev * B_ + b) * N1_ + j1];
        }
        const float* s0p = s0_all + (size_t)(t - 1) * N0_ * B_;
        const float* p0p = p0_all + (size_t)(t - 1) * N0_ * B_;
        #pragma unroll 2
        for (int ii = 0; ii < 128; ++ii) {
            const int i = i0 + ii;
            float4 p0r[4], s0r[4], s0tr[4];
            ld_row4(p0r,  p0p + (size_t)i * B_);
            ld_row4(s0r,  s0p + (size_t)i * B_);
            ld_row4(s0tr, s0t + (size_t)i * B_);
            size_t wi = (size_t)i * N1_;
            float w0 = Wa[wi + j0];
            float w1 = Wa[wi + j1];
            float t1a = dot16(p0r, s1v0), t2a = dot16(s0r, q0v0);
            float t1b = dot16(p0r, s1v1), t2b = dot16(s0r, q0v1);
            float wn0 = __fadd_rn(w0, __fmul_rn(0.01f, __fsub_rn(t1a, t2a)));
            float wn1 = __fadd_rn(w1, __fmul_rn(0.01f, __fsub_rn(t1b, t2b)));
            wn0 = fminf(fmaxf(wn0, -1.0f), 1.0f);
            wn1 = fminf(fmaxf(wn1, -1.0f), 1.0f);
            if (store_w) { Wa[wi + j0] = wn0; Wa[wi + j1] = wn1; }
            acc16(acc0, s0tr, wn0);
            acc16(acc1, s0tr, wn1);
        }
    } else {
        #pragma unroll 2
        for (int ii = 0; ii < 128; ++ii) {
            const int i = i0 + ii;
            float4 s0tr[4];
            ld_row4(s0tr, s0t + (size_t)i * B_);
            size_t wi = (size_t)i * N1_;
            float w0 = Wa[wi + j0];
            float w1 = Wa[wi + j1];
            acc16(acc0, s0tr, w0);
            acc16(acc1, s0tr, w1);
        }
    }
    #pragma unroll
    for (int b = 0; b < B_; ++b) {
        pa[((size_t)chunk * B_ + b) * N1_ + j0] = acc0[b];
        pa[((size_t)chunk * B_ + b) * N1_ + j1] = acc1[b];
    }
}

// ---- LIF layer 1: reduce pa (fixed order), V1/r1, s1, q0, p1 ----
__global__ __launch_bounds__(256) void lif1_kernel(
    const float* __restrict__ pa, float* __restrict__ V1, float* __restrict__ r1,
    float* __restrict__ s1_bj, float* __restrict__ s1_jb,
    float* __restrict__ q0_bj, float* __restrict__ p1_jb, int t)
{
    int tid = blockIdx.x * 256 + threadIdx.x;      // 65536 = B*N1
    int b = tid >> 12, j = tid & (N1_ - 1);
    float y = 0.f;
    for (int c = 0; c < 32; ++c) y += pa[((size_t)c * B_ + b) * N1_ + j];
    float V = __fadd_rn(__fmul_rn(0.9f, V1[tid]), y);
    float rr = r1[tid];
    bool spk = (V > 1.0f) && (rr <= 0.0f);
    float s = spk ? 1.0f : 0.0f;
    V1[tid] = spk ? 0.0f : V;
    r1[tid] = spk ? 2.0f : fmaxf(rr - 1.0f, 0.0f);
    int cur = t & 1, prev = 1 - cur;
    s1_bj[(size_t)cur * B_ * N1_ + tid] = s;
    s1_jb[(size_t)cur * B_ * N1_ + (size_t)j * B_ + b] = s;
    float q0 = __fadd_rn(__fmul_rn(0.95f, q0_bj[(size_t)prev * B_ * N1_ + tid]), s);
    q0_bj[(size_t)cur * B_ * N1_ + tid] = q0;
    float p1 = __fadd_rn(__fmul_rn(0.95f, p1_jb[(size_t)prev * B_ * N1_ + (size_t)j * B_ + b]), s);
    p1_jb[(size_t)cur * B_ * N1_ + (size_t)j * B_ + b] = p1;
}

// ---- fused: apply dWb(t-1)+clip, then partial y2(t) = s1(t) @ Wb ----
// grid 256: 4 k-tiles(512, KT=2) x 64 j-chunks(64). Partials pb: (64,B,N2).
__global__ __launch_bounds__(256) void kb_kernel(
    float* __restrict__ Wb,            // (N1, N2) in-place
    const float* __restrict__ s1_jb,   // (2, N1, B)
    const float* __restrict__ p1_jb,   // (2, N1, B)
    const float* __restrict__ s2_bk,   // (2, B, N2)
    const float* __restrict__ q1_bk,   // (2, B, N2)
    float* __restrict__ pb, int t, int store_w)
{
    const int kt = blockIdx.x >> 6;         // 0..3
    const int chunk = blockIdx.x & 63;      // 0..63
    const int k0 = kt * 512 + threadIdx.x;
    const int k1 = k0 + 256;
    const int j0 = chunk * 64;
    const int cur = t & 1, prev = 1 - cur;

    float acc0[B_], acc1[B_];
    #pragma unroll
    for (int b = 0; b < B_; ++b) { acc0[b] = 0.f; acc1[b] = 0.f; }

    const float* s1c = s1_jb + (size_t)cur * N1_ * B_;

    if (t > 0) {
        float s2v0[B_], q1v0[B_], s2v1[B_], q1v1[B_];
        #pragma unroll
        for (int b = 0; b < B_; ++b) {
            s2v0[b] = s2_bk[((size_t)prev * B_ + b) * N2_ + k0];
            q1v0[b] = q1_bk[((size_t)prev * B_ + b) * N2_ + k0];
            s2v1[b] = s2_bk[((size_t)prev * B_ + b) * N2_ + k1];
            q1v1[b] = q1_bk[((size_t)prev * B_ + b) * N2_ + k1];
        }
        const float* p1p = p1_jb + (size_t)prev * N1_ * B_;
        const float* s1p = s1_jb + (size_t)prev * N1_ * B_;
        #pragma unroll 2
        for (int jj = j0; jj < j0 + 64; ++jj) {
            float4 p1r[4], s1pr[4], s1cr[4];
            ld_row4(p1r,  p1p + (size_t)jj * B_);
            ld_row4(s1pr, s1p + (size_t)jj * B_);
            ld_row4(s1cr, s1c + (size_t)jj * B_);
            size_t wi = (size_t)jj * N2_;
            float w0 = Wb[wi + k0];
            float w1 = Wb[wi + k1];
            float t1a = dot16(p1r, s2v0), t2a = dot16(s1pr, q1v0);
            float t1b = dot16(p1r, s2v1), t2b = dot16(s1pr, q1v1);
            float wn0 = __fadd_rn(w0, __fmul_rn(0.01f, __fsub_rn(t1a, t2a)));
            float wn1 = __fadd_rn(w1, __fmul_rn(0.01f, __fsub_rn(t1b, t2b)));
            wn0 = fminf(fmaxf(wn0, -1.0f), 1.0f);
            wn1 = fminf(fmaxf(wn1, -1.0f), 1.0f);
            if (store_w) { Wb[wi + k0] = wn0; Wb[wi + k1] = wn1; }
            acc16(acc0, s1cr, wn0);
            acc16(acc1, s1cr, wn1);
        }
    } else {
        #pragma unroll 2
        for (int jj = j0; jj < j0 + 64; ++jj) {
            float4 s1cr[4];
            ld_row4(s1cr, s1c + (size_t)jj * B_);
            size_t wi = (size_t)jj * N2_;
            float w0 = Wb[wi + k0];
            float w1 = Wb[wi + k1];
            acc16(acc0, s1cr, w0);
            acc16(acc1, s1cr, w1);
        }
    }
    #pragma unroll
    for (int b = 0; b < B_; ++b) {
        pb[((size_t)chunk * B_ + b) * N2_ + k0] = acc0[b];
        pb[((size_t)chunk * B_ + b) * N2_ + k1] = acc1[b];
    }
}

// ---- LIF layer 2: reduce pb, V2/r2, s2, q1, spike counts ----
__global__ __launch_bounds__(256) void lif2_kernel(
    const float* __restrict__ pb, float* __restrict__ V2, float* __restrict__ r2,
    float* __restrict__ s2_bk, float* __restrict__ q1_bk,
    float* __restrict__ counts, int t)
{
    int tid = blockIdx.x * 256 + threadIdx.x;      // 32768 = B*N2
    int b = tid >> 11, k = tid & (N2_ - 1);
    float y = 0.f;
    for (int c = 0; c < 64; ++c) y += pb[((size_t)c * B_ + b) * N2_ + k];
    float V = __fadd_rn(__fmul_rn(0.9f, V2[tid]), y);
    float rr = r2[tid];
    bool spk = (V > 1.0f) && (rr <= 0.0f);
    float s = spk ? 1.0f : 0.0f;
    V2[tid] = spk ? 0.0f : V;
    r2[tid] = spk ? 2.0f : fmaxf(rr - 1.0f, 0.0f);
    int cur = t & 1, prev = 1 - cur;
    s2_bk[(size_t)cur * B_ * N2_ + tid] = s;
    float q1 = __fadd_rn(__fmul_rn(0.95f, q1_bk[(size_t)prev * B_ * N2_ + tid]), s);
    q1_bk[(size_t)cur * B_ * N2_ + tid] = q1;
    counts[tid] = counts[tid] + s;
}

// ---- decode: out = counts @ W_dec + b_dec ----
__global__ __launch_bounds__(256) void decode_kernel(
    const float* __restrict__ counts, const float* __restrict__ W_dec,
    const float* __restrict__ b_dec, float* __restrict__ out)
{
    int tid = threadIdx.x;
    if (tid < B_ * NC_) {
        int b = tid / NC_, c = tid % NC_;
        float a = 0.f;
        for (int k = 0; k < N2_; ++k)
            a = fmaf(counts[(size_t)b * N2_ + k], W_dec[(size_t)k * NC_ + c], a);
        out[tid] = __fadd_rn(a, b_dec[c]);
    }
}

extern "C" void kernel_launch(void* const* d_in, const int* in_sizes, int n_in,
                              void* d_out, int out_size, void* d_ws, size_t ws_size,
                              hipStream_t stream) {
    const float* x     = (const float*)d_in[0];
    const float* u     = (const float*)d_in[1];
    const float* W_enc = (const float*)d_in[2];
    const float* b_enc = (const float*)d_in[3];
    float* Wa          = (float*)d_in[4];   // updated in place; harness restores before every timed launch
    float* Wb          = (float*)d_in[5];
    const float* W_dec = (const float*)d_in[6];
    const float* b_dec = (const float*)d_in[7];
    float* out         = (float*)d_out;

    float* ws = (float*)d_ws;
    size_t off = 0;
    float* rates  = ws + off; off += (size_t)B_ * N0_;
    float* s0_all = ws + off; off += (size_t)T_ * N0_ * B_;
    float* p0_all = ws + off; off += (size_t)T_ * N0_ * B_;
    float* s1_bj  = ws + off; off += 2 * (size_t)B_ * N1_;
    float* s1_jb  = ws + off; off += 2 * (size_t)B_ * N1_;
    float* pa     = ws + off; off += 32 * (size_t)B_ * N1_;
    float* pb     = ws + off; off += 64 * (size_t)B_ * N2_;
    float* zblock = ws + off;                       // everything below is zero-init state
    float* q0_bj  = ws + off; off += 2 * (size_t)B_ * N1_;
    float* p1_jb  = ws + off; off += 2 * (size_t)B_ * N1_;
    float* q1_bk  = ws + off; off += 2 * (size_t)B_ * N2_;
    float* s2_bk  = ws + off; off += 2 * (size_t)B_ * N2_;
    float* V1     = ws + off; off += (size_t)B_ * N1_;
    float* r1     = ws + off; off += (size_t)B_ * N1_;
    float* V2     = ws + off; off += (size_t)B_ * N2_;
    float* r2     = ws + off; off += (size_t)B_ * N2_;
    float* counts = ws + off; off += (size_t)B_ * N2_;
    size_t zbytes = (size_t)((ws + off) - zblock) * sizeof(float);

    hipMemsetAsync(zblock, 0, zbytes, stream);
    rates_kernel<<<256, 256, 0, stream>>>(x, W_enc, b_enc, rates);
    layer0_kernel<<<256, 256, 0, stream>>>(u, rates, s0_all, p0_all);
    for (int t = 0; t < T_; ++t) {
        int store_w = (t < T_ - 1) ? 1 : 0;
        ka_kernel<<<256, 256, 0, stream>>>(Wa, s0_all, p0_all, s1_bj, q0_bj, pa, t, store_w);
        lif1_kernel<<<256, 256, 0, stream>>>(pa, V1, r1, s1_bj, s1_jb, q0_bj, p1_jb, t);
        kb_kernel<<<256, 256, 0, stream>>>(Wb, s1_jb, p1_jb, s2_bk, q1_bk, pb, t, store_w);
        lif2_kernel<<<128, 256, 0, stream>>>(pb, V2, r2, s2_bk, q1_bk, counts, t);
    }
    decode_kernel<<<1, 256, 0, stream>>>(counts, W_dec, b_dec, out);
}

// Round 3
// 10260.493 us; speedup vs baseline: 1.5883x; 1.1595x over previous
//
#include <hip/hip_runtime.h>
#include <math.h>

#define B_  16
#define D_  2048
#define T_  100
#define N0_ 4096
#define N1_ 4096
#define N2_ 2048
#define NC_ 10

// ---------------- rates = sigmoid(x @ W_enc + b_enc) ----------------
__global__ __launch_bounds__(256) void rates_kernel(
    const float* __restrict__ x, const float* __restrict__ W_enc,
    const float* __restrict__ b_enc, float* __restrict__ rates)
{
    int tid = blockIdx.x * 256 + threadIdx.x;      // 65536 = B*N0
    int b = tid >> 12, i = tid & (N0_ - 1);
    const float* xr = x + b * D_;
    float acc = 0.f;
    for (int d = 0; d < D_; ++d)
        acc = fmaf(xr[d], W_enc[(size_t)d * N0_ + i], acc);
    float z = __fadd_rn(acc, b_enc[i]);
    rates[tid] = 1.0f / (1.0f + expf(-z));         // (B, N0)
}

// ---- layer-0 LIF over all T (independent of weights): s0, p0 in (T,N0,B) ----
__global__ __launch_bounds__(256) void layer0_kernel(
    const float* __restrict__ u, const float* __restrict__ rates,
    float* __restrict__ s0_all, float* __restrict__ p0_all)
{
    int tid = blockIdx.x * 256 + threadIdx.x;      // 65536
    int b = tid & (B_ - 1), i = tid >> 4;
    float rate = rates[b * N0_ + i];
    const float* ub = u + (size_t)b * T_ * N0_ + i;  // u is (B,T,N0)
    float V = 0.f, refr = 0.f, p0 = 0.f;
    for (int t = 0; t < T_; ++t) {
        float uv = ub[(size_t)t * N0_];
        float s_in = (uv < rate) ? 1.0f : 0.0f;
        V = __fadd_rn(__fmul_rn(0.9f, V), s_in);
        bool spk = (V > 1.0f) && (refr <= 0.0f);
        float s = spk ? 1.0f : 0.0f;
        V = spk ? 0.0f : V;
        refr = spk ? 2.0f : fmaxf(refr - 1.0f, 0.0f);
        p0 = __fadd_rn(__fmul_rn(0.95f, p0), s);   // trace after spike, per reference
        size_t idx = ((size_t)t * N0_ + i) * B_ + b;
        s0_all[idx] = s;
        p0_all[idx] = p0;
    }
}

// dot16 in fixed b-ascending order
__device__ __forceinline__ float dot16(const float4 r[4], const float* v) {
    float t = 0.f;
    t = fmaf(r[0].x, v[0], t);  t = fmaf(r[0].y, v[1], t);
    t = fmaf(r[0].z, v[2], t);  t = fmaf(r[0].w, v[3], t);
    t = fmaf(r[1].x, v[4], t);  t = fmaf(r[1].y, v[5], t);
    t = fmaf(r[1].z, v[6], t);  t = fmaf(r[1].w, v[7], t);
    t = fmaf(r[2].x, v[8], t);  t = fmaf(r[2].y, v[9], t);
    t = fmaf(r[2].z, v[10], t); t = fmaf(r[2].w, v[11], t);
    t = fmaf(r[3].x, v[12], t); t = fmaf(r[3].y, v[13], t);
    t = fmaf(r[3].z, v[14], t); t = fmaf(r[3].w, v[15], t);
    return t;
}
__device__ __forceinline__ void acc16(float* acc, const float4 r[4], float w) {
    acc[0]  = fmaf(r[0].x, w, acc[0]);  acc[1]  = fmaf(r[0].y, w, acc[1]);
    acc[2]  = fmaf(r[0].z, w, acc[2]);  acc[3]  = fmaf(r[0].w, w, acc[3]);
    acc[4]  = fmaf(r[1].x, w, acc[4]);  acc[5]  = fmaf(r[1].y, w, acc[5]);
    acc[6]  = fmaf(r[1].z, w, acc[6]);  acc[7]  = fmaf(r[1].w, w, acc[7]);
    acc[8]  = fmaf(r[2].x, w, acc[8]);  acc[9]  = fmaf(r[2].y, w, acc[9]);
    acc[10] = fmaf(r[2].z, w, acc[10]); acc[11] = fmaf(r[2].w, w, acc[11]);
    acc[12] = fmaf(r[3].x, w, acc[12]); acc[13] = fmaf(r[3].y, w, acc[13]);
    acc[14] = fmaf(r[3].z, w, acc[14]); acc[15] = fmaf(r[3].w, w, acc[15]);
}
__device__ __forceinline__ void ld_row4(float4 r[4], const float* p) {
    const float4* p4 = (const float4*)p;   // 64B-aligned (i*B_*4)
    r[0] = p4[0]; r[1] = p4[1]; r[2] = p4[2]; r[3] = p4[3];
}

// ---- fused: apply dWa(t-1)+clip, then partial y1(t) = s0(t) @ Wa ----
// grid 512: 8 j-tiles(512, JT=2) x 64 i-chunks(64 rows) -> 2 blocks/CU.
// Explicit prefetch of next iteration's Wa pair hides L2/L3 latency.
__global__ __launch_bounds__(256) void ka_kernel(
    float* __restrict__ Wa,            // (N0, N1) in-place
    const float* __restrict__ s0_all,  // (T, N0, B)
    const float* __restrict__ p0_all,  // (T, N0, B)
    const float* __restrict__ s1_bj,   // (2, B, N1)
    const float* __restrict__ q0_bj,   // (2, B, N1)
    float* __restrict__ pa, int t, int store_w)
{
    const int jt = blockIdx.x >> 6;         // 0..7
    const int chunk = blockIdx.x & 63;      // 0..63
    const int j0 = jt * 512 + threadIdx.x;
    const int j1 = j0 + 256;
    const int i0 = chunk * 64;
    const int prev = 1 - (t & 1);

    float acc0[B_], acc1[B_];
    #pragma unroll
    for (int b = 0; b < B_; ++b) { acc0[b] = 0.f; acc1[b] = 0.f; }

    const float* s0t = s0_all + (size_t)t * N0_ * B_;

    if (t > 0) {
        float s1v0[B_], q0v0[B_], s1v1[B_], q0v1[B_];
        #pragma unroll
        for (int b = 0; b < B_; ++b) {
            s1v0[b] = s1_bj[((size_t)prev * B_ + b) * N1_ + j0];
            q0v0[b] = q0_bj[((size_t)prev * B_ + b) * N1_ + j0];
            s1v1[b] = s1_bj[((size_t)prev * B_ + b) * N1_ + j1];
            q0v1[b] = q0_bj[((size_t)prev * B_ + b) * N1_ + j1];
        }
        const float* s0p = s0_all + (size_t)(t - 1) * N0_ * B_;
        const float* p0p = p0_all + (size_t)(t - 1) * N0_ * B_;
        float w0 = Wa[(size_t)i0 * N1_ + j0];
        float w1 = Wa[(size_t)i0 * N1_ + j1];
        for (int ii = 0; ii < 64; ++ii) {
            const int i = i0 + ii;
            const int ip = (ii < 63) ? (i + 1) : i;        // prefetch next row's weights
            float w0n = Wa[(size_t)ip * N1_ + j0];
            float w1n = Wa[(size_t)ip * N1_ + j1];
            float4 p0r[4], s0r[4], s0tr[4];
            ld_row4(p0r,  p0p + (size_t)i * B_);
            ld_row4(s0r,  s0p + (size_t)i * B_);
            ld_row4(s0tr, s0t + (size_t)i * B_);
            float t1a = dot16(p0r, s1v0), t2a = dot16(s0r, q0v0);
            float t1b = dot16(p0r, s1v1), t2b = dot16(s0r, q0v1);
            float wn0 = __fadd_rn(w0, __fmul_rn(0.01f, __fsub_rn(t1a, t2a)));
            float wn1 = __fadd_rn(w1, __fmul_rn(0.01f, __fsub_rn(t1b, t2b)));
            wn0 = fminf(fmaxf(wn0, -1.0f), 1.0f);
            wn1 = fminf(fmaxf(wn1, -1.0f), 1.0f);
            if (store_w) {
                Wa[(size_t)i * N1_ + j0] = wn0;
                Wa[(size_t)i * N1_ + j1] = wn1;
            }
            acc16(acc0, s0tr, wn0);
            acc16(acc1, s0tr, wn1);
            w0 = w0n; w1 = w1n;
        }
    } else {
        for (int ii = 0; ii < 64; ++ii) {
            const int i = i0 + ii;
            float4 s0tr[4];
            ld_row4(s0tr, s0t + (size_t)i * B_);
            size_t wi = (size_t)i * N1_;
            float w0 = Wa[wi + j0];
            float w1 = Wa[wi + j1];
            acc16(acc0, s0tr, w0);
            acc16(acc1, s0tr, w1);
        }
    }
    #pragma unroll
    for (int b = 0; b < B_; ++b) {
        pa[((size_t)chunk * B_ + b) * N1_ + j0] = acc0[b];
        pa[((size_t)chunk * B_ + b) * N1_ + j1] = acc1[b];
    }
}

// ---- LIF layer 1: reduce pa (fixed order, 64 chunks), V1/r1, s1, q0, p1 ----
__global__ __launch_bounds__(256) void lif1_kernel(
    const float* __restrict__ pa, float* __restrict__ V1, float* __restrict__ r1,
    float* __restrict__ s1_bj, float* __restrict__ s1_jb,
    float* __restrict__ q0_bj, float* __restrict__ p1_jb, int t)
{
    int tid = blockIdx.x * 256 + threadIdx.x;      // 65536 = B*N1
    int b = tid >> 12, j = tid & (N1_ - 1);
    float y = 0.f;
    for (int c = 0; c < 64; ++c) y += pa[((size_t)c * B_ + b) * N1_ + j];
    float V = __fadd_rn(__fmul_rn(0.9f, V1[tid]), y);
    float rr = r1[tid];
    bool spk = (V > 1.0f) && (rr <= 0.0f);
    float s = spk ? 1.0f : 0.0f;
    V1[tid] = spk ? 0.0f : V;
    r1[tid] = spk ? 2.0f : fmaxf(rr - 1.0f, 0.0f);
    int cur = t & 1, prev = 1 - cur;
    s1_bj[(size_t)cur * B_ * N1_ + tid] = s;
    s1_jb[(size_t)cur * B_ * N1_ + (size_t)j * B_ + b] = s;
    float q0 = __fadd_rn(__fmul_rn(0.95f, q0_bj[(size_t)prev * B_ * N1_ + tid]), s);
    q0_bj[(size_t)cur * B_ * N1_ + tid] = q0;
    float p1 = __fadd_rn(__fmul_rn(0.95f, p1_jb[(size_t)prev * B_ * N1_ + (size_t)j * B_ + b]), s);
    p1_jb[(size_t)cur * B_ * N1_ + (size_t)j * B_ + b] = p1;
}

// ---- fused: apply dWb(t-1)+clip, then partial y2(t) = s1(t) @ Wb ----
// grid 512: 4 k-tiles(512, KT=2) x 128 j-chunks(32 rows) -> 2 blocks/CU.
__global__ __launch_bounds__(256) void kb_kernel(
    float* __restrict__ Wb,            // (N1, N2) in-place
    const float* __restrict__ s1_jb,   // (2, N1, B)
    const float* __restrict__ p1_jb,   // (2, N1, B)
    const float* __restrict__ s2_bk,   // (2, B, N2)
    const float* __restrict__ q1_bk,   // (2, B, N2)
    float* __restrict__ pb, int t, int store_w)
{
    const int kt = blockIdx.x >> 7;         // 0..3
    const int chunk = blockIdx.x & 127;     // 0..127
    const int k0 = kt * 512 + threadIdx.x;
    const int k1 = k0 + 256;
    const int j0 = chunk * 32;
    const int cur = t & 1, prev = 1 - cur;

    float acc0[B_], acc1[B_];
    #pragma unroll
    for (int b = 0; b < B_; ++b) { acc0[b] = 0.f; acc1[b] = 0.f; }

    const float* s1c = s1_jb + (size_t)cur * N1_ * B_;

    if (t > 0) {
        float s2v0[B_], q1v0[B_], s2v1[B_], q1v1[B_];
        #pragma unroll
        for (int b = 0; b < B_; ++b) {
            s2v0[b] = s2_bk[((size_t)prev * B_ + b) * N2_ + k0];
            q1v0[b] = q1_bk[((size_t)prev * B_ + b) * N2_ + k0];
            s2v1[b] = s2_bk[((size_t)prev * B_ + b) * N2_ + k1];
            q1v1[b] = q1_bk[((size_t)prev * B_ + b) * N2_ + k1];
        }
        const float* p1p = p1_jb + (size_t)prev * N1_ * B_;
        const float* s1p = s1_jb + (size_t)prev * N1_ * B_;
        float w0 = Wb[(size_t)j0 * N2_ + k0];
        float w1 = Wb[(size_t)j0 * N2_ + k1];
        for (int jj = j0; jj < j0 + 32; ++jj) {
            const int jp = (jj < j0 + 31) ? (jj + 1) : jj;  // prefetch next row's weights
            float w0n = Wb[(size_t)jp * N2_ + k0];
            float w1n = Wb[(size_t)jp * N2_ + k1];
            float4 p1r[4], s1pr[4], s1cr[4];
            ld_row4(p1r,  p1p + (size_t)jj * B_);
            ld_row4(s1pr, s1p + (size_t)jj * B_);
            ld_row4(s1cr, s1c + (size_t)jj * B_);
            float t1a = dot16(p1r, s2v0), t2a = dot16(s1pr, q1v0);
            float t1b = dot16(p1r, s2v1), t2b = dot16(s1pr, q1v1);
            float wn0 = __fadd_rn(w0, __fmul_rn(0.01f, __fsub_rn(t1a, t2a)));
            float wn1 = __fadd_rn(w1, __fmul_rn(0.01f, __fsub_rn(t1b, t2b)));
            wn0 = fminf(fmaxf(wn0, -1.0f), 1.0f);
            wn1 = fminf(fmaxf(wn1, -1.0f), 1.0f);
            if (store_w) {
                Wb[(size_t)jj * N2_ + k0] = wn0;
                Wb[(size_t)jj * N2_ + k1] = wn1;
            }
            acc16(acc0, s1cr, wn0);
            acc16(acc1, s1cr, wn1);
            w0 = w0n; w1 = w1n;
        }
    } else {
        for (int jj = j0; jj < j0 + 32; ++jj) {
            float4 s1cr[4];
            ld_row4(s1cr, s1c + (size_t)jj * B_);
            size_t wi = (size_t)jj * N2_;
            float w0 = Wb[wi + k0];
            float w1 = Wb[wi + k1];
            acc16(acc0, s1cr, w0);
            acc16(acc1, s1cr, w1);
        }
    }
    #pragma unroll
    for (int b = 0; b < B_; ++b) {
        pb[((size_t)chunk * B_ + b) * N2_ + k0] = acc0[b];
        pb[((size_t)chunk * B_ + b) * N2_ + k1] = acc1[b];
    }
}

// ---- LIF layer 2: reduce pb (128 chunks), V2/r2, s2, q1, spike counts ----
__global__ __launch_bounds__(256) void lif2_kernel(
    const float* __restrict__ pb, float* __restrict__ V2, float* __restrict__ r2,
    float* __restrict__ s2_bk, float* __restrict__ q1_bk,
    float* __restrict__ counts, int t)
{
    int tid = blockIdx.x * 256 + threadIdx.x;      // 32768 = B*N2
    int b = tid >> 11, k = tid & (N2_ - 1);
    float y = 0.f;
    for (int c = 0; c < 128; ++c) y += pb[((size_t)c * B_ + b) * N2_ + k];
    float V = __fadd_rn(__fmul_rn(0.9f, V2[tid]), y);
    float rr = r2[tid];
    bool spk = (V > 1.0f) && (rr <= 0.0f);
    float s = spk ? 1.0f : 0.0f;
    V2[tid] = spk ? 0.0f : V;
    r2[tid] = spk ? 2.0f : fmaxf(rr - 1.0f, 0.0f);
    int cur = t & 1, prev = 1 - cur;
    s2_bk[(size_t)cur * B_ * N2_ + tid] = s;
    float q1 = __fadd_rn(__fmul_rn(0.95f, q1_bk[(size_t)prev * B_ * N2_ + tid]), s);
    q1_bk[(size_t)cur * B_ * N2_ + tid] = q1;
    counts[tid] = counts[tid] + s;
}

// ---- decode: out = counts @ W_dec + b_dec ----
__global__ __launch_bounds__(256) void decode_kernel(
    const float* __restrict__ counts, const float* __restrict__ W_dec,
    const float* __restrict__ b_dec, float* __restrict__ out)
{
    int tid = threadIdx.x;
    if (tid < B_ * NC_) {
        int b = tid / NC_, c = tid % NC_;
        float a = 0.f;
        for (int k = 0; k < N2_; ++k)
            a = fmaf(counts[(size_t)b * N2_ + k], W_dec[(size_t)k * NC_ + c], a);
        out[tid] = __fadd_rn(a, b_dec[c]);
    }
}

extern "C" void kernel_launch(void* const* d_in, const int* in_sizes, int n_in,
                              void* d_out, int out_size, void* d_ws, size_t ws_size,
                              hipStream_t stream) {
    const float* x     = (const float*)d_in[0];
    const float* u     = (const float*)d_in[1];
    const float* W_enc = (const float*)d_in[2];
    const float* b_enc = (const float*)d_in[3];
    float* Wa          = (float*)d_in[4];   // updated in place; harness restores before every timed launch
    float* Wb          = (float*)d_in[5];
    const float* W_dec = (const float*)d_in[6];
    const float* b_dec = (const float*)d_in[7];
    float* out         = (float*)d_out;

    float* ws = (float*)d_ws;
    size_t off = 0;
    float* rates  = ws + off; off += (size_t)B_ * N0_;
    float* s0_all = ws + off; off += (size_t)T_ * N0_ * B_;
    float* p0_all = ws + off; off += (size_t)T_ * N0_ * B_;
    float* s1_bj  = ws + off; off += 2 * (size_t)B_ * N1_;
    float* s1_jb  = ws + off; off += 2 * (size_t)B_ * N1_;
    float* pa     = ws + off; off += 64 * (size_t)B_ * N1_;
    float* pb     = ws + off; off += 128 * (size_t)B_ * N2_;
    float* zblock = ws + off;                       // everything below is zero-init state
    float* q0_bj  = ws + off; off += 2 * (size_t)B_ * N1_;
    float* p1_jb  = ws + off; off += 2 * (size_t)B_ * N1_;
    float* q1_bk  = ws + off; off += 2 * (size_t)B_ * N2_;
    float* s2_bk  = ws + off; off += 2 * (size_t)B_ * N2_;
    float* V1     = ws + off; off += (size_t)B_ * N1_;
    float* r1     = ws + off; off += (size_t)B_ * N1_;
    float* V2     = ws + off; off += (size_t)B_ * N2_;
    float* r2     = ws + off; off += (size_t)B_ * N2_;
    float* counts = ws + off; off += (size_t)B_ * N2_;
    size_t zbytes = (size_t)((ws + off) - zblock) * sizeof(float);

    hipMemsetAsync(zblock, 0, zbytes, stream);
    rates_kernel<<<256, 256, 0, stream>>>(x, W_enc, b_enc, rates);
    layer0_kernel<<<256, 256, 0, stream>>>(u, rates, s0_all, p0_all);
    for (int t = 0; t < T_; ++t) {
        int store_w = (t < T_ - 1) ? 1 : 0;
        ka_kernel<<<512, 256, 0, stream>>>(Wa, s0_all, p0_all, s1_bj, q0_bj, pa, t, store_w);
        lif1_kernel<<<256, 256, 0, stream>>>(pa, V1, r1, s1_bj, s1_jb, q0_bj, p1_jb, t);
        kb_kernel<<<512, 256, 0, stream>>>(Wb, s1_jb, p1_jb, s2_bk, q1_bk, pb, t, store_w);
        lif2_kernel<<<128, 256, 0, stream>>>(pb, V2, r2, s2_bk, q1_bk, counts, t);
    }
    decode_kernel<<<1, 256, 0, stream>>>(counts, W_dec, b_dec, out);
}